// Round 1
// baseline (22943.954 us; speedup 1.0000x reference)
//
#include <hip/hip_runtime.h>
#include <cmath>

#define H_DIM 1024
#define I_DIMM 256
#define B_DIM 64
#define T_DIM 256

__device__ __forceinline__ float sigmoidf_(float x) {
    return 1.0f / (1.0f + expf(-x));
}

// One LSTM timestep.
// grid = 256 blocks x 256 threads. Block `blk` owns h-columns [blk*4, blk*4+4)
// => 16 gate columns (4 gates x 4 cols).
// 4 waves per block: wave = (khalf, cset); khalf splits K=1280 into [0,640)/[640,1280),
// cset splits the 4 h-cols into 2 pairs. Each wave: 8 gate-col dot-products over K/2,
// lane = batch row. Partials combined via LDS, then activations + c/h update.
__global__ __launch_bounds__(256) void lstm_step_kernel(
    const float* __restrict__ h_in,   // [64][1024]
    float* __restrict__ h_out,        // [64][1024]
    float* __restrict__ c_T,          // [1024][64] (transposed cell state)
    const float* __restrict__ x,      // [64][256][256]
    int t,
    const float* __restrict__ Wih,    // [4096][256]
    const float* __restrict__ Whh,    // [4096][1024]
    const float* __restrict__ bih,    // [4096]
    const float* __restrict__ bhh)    // [4096]
{
    __shared__ float tileA[2][64][132];     // [half][batch][k-tile of 128, +4 pad]
    __shared__ float gpart[2][4][4][64];    // [khalf][gate][jcol][batch]

    const int tid  = threadIdx.x;
    const int blk  = blockIdx.x;
    const int wid  = __builtin_amdgcn_readfirstlane(tid >> 6);
    const int lane = tid & 63;
    const int khalf = wid >> 1;
    const int cset  = wid & 1;

    float acc[8] = {0.f,0.f,0.f,0.f,0.f,0.f,0.f,0.f};

    const int r = tid >> 2;   // staging: batch row
    const int q = tid & 3;    // staging: 32-float quarter of the 128-wide tile

    for (int it = 0; it < 5; ++it) {
        // ---- stage both K-half tiles: A = [h_in | x_t], columns [k0, k0+128) ----
        #pragma unroll
        for (int half = 0; half < 2; ++half) {
            const int k0 = half * 640 + it * 128;   // never straddles the 1024 boundary
            const float* src;
            if (k0 < 1024) src = h_in + r * H_DIM + k0 + q * 32;
            else           src = x + r * (T_DIM * I_DIMM) + t * I_DIMM + (k0 - 1024) + q * 32;
            #pragma unroll
            for (int j = 0; j < 8; ++j) {
                float4 v = *(const float4*)(src + j * 4);
                *(float4*)&tileA[half][r][q * 32 + j * 4] = v;
            }
        }
        __syncthreads();

        // ---- compute on this wave's K-half ----
        const int kstart = khalf * 640 + it * 128;
        const float* wbase; int ldw, koff;
        if (kstart < 1024) { wbase = Whh; ldw = H_DIM;  koff = kstart; }
        else               { wbase = Wih; ldw = I_DIMM; koff = kstart - 1024; }

        const float* wrow[8];
        #pragma unroll
        for (int cc = 0; cc < 8; ++cc) {
            const int g  = cc >> 1;
            const int jj = cc & 1;
            const int gc = g * H_DIM + blk * 4 + cset * 2 + jj;
            wrow[cc] = wbase + gc * ldw + koff;
        }

        #pragma unroll 2
        for (int kk = 0; kk < 128; kk += 4) {
            const float4 a4 = *(const float4*)&tileA[khalf][lane][kk];
            #pragma unroll
            for (int cc = 0; cc < 8; ++cc) {
                const float4 w4 = *(const float4*)(wrow[cc] + kk);
                acc[cc] += a4.x * w4.x + a4.y * w4.y + a4.z * w4.z + a4.w * w4.w;
            }
        }
        __syncthreads();
    }

    // ---- write K-half partials ----
    #pragma unroll
    for (int cc = 0; cc < 8; ++cc) {
        const int g  = cc >> 1;
        const int jj = cc & 1;
        gpart[khalf][g][cset * 2 + jj][lane] = acc[cc];
    }
    __syncthreads();

    // ---- combine + activations + state update: thread -> (batch b, col j) ----
    {
        const int b   = tid >> 2;
        const int j   = tid & 3;
        const int col = blk * 4 + j;
        float pre[4];
        #pragma unroll
        for (int g = 0; g < 4; ++g) {
            pre[g] = gpart[0][g][j][b] + gpart[1][g][j][b]
                   + bih[g * H_DIM + col] + bhh[g * H_DIM + col];
        }
        const float i_ = sigmoidf_(pre[0]);
        const float f_ = sigmoidf_(pre[1]);
        const float g_ = tanhf(pre[2]);
        const float o_ = sigmoidf_(pre[3]);
        const float c_old = c_T[col * 64 + b];
        const float c_new = f_ * c_old + i_ * g_;
        c_T[col * 64 + b] = c_new;
        h_out[b * H_DIM + col] = o_ * tanhf(c_new);
    }
}

// Tail MLP: a = PReLU(additional @ fcc_W^T + fcc_b); out[b] = [dh, a] @ fc_W^T + fc_b
// grid = 64 blocks (one per batch row) x 256 threads.
__global__ __launch_bounds__(256) void tail_kernel(
    const float* __restrict__ dh,       // [64][1024]
    const float* __restrict__ addl,     // [64][128]
    const float* __restrict__ fccW,     // [256][128]
    const float* __restrict__ fccb,     // [256]
    const float* __restrict__ fcW,      // [1][1280]
    const float* __restrict__ fcb,      // [1]
    const float* __restrict__ prelu_a,  // [1]
    float* __restrict__ out)            // [64]
{
    __shared__ float a_lds[256];
    __shared__ float red[256];
    const int b = blockIdx.x;
    const int t = threadIdx.x;

    // phase 1: a[b][t]
    float s = fccb[t];
    const float* wr = fccW + t * 128;
    const float* ar = addl + b * 128;
    #pragma unroll 4
    for (int k = 0; k < 128; ++k) s += ar[k] * wr[k];
    const float pa = *prelu_a;
    a_lds[t] = (s >= 0.f) ? s : pa * s;
    __syncthreads();

    // phase 2: dot with fc_W
    float acc = 0.f;
    for (int k = t; k < 1024; k += 256) acc += dh[b * H_DIM + k] * fcW[k];
    acc += a_lds[t] * fcW[1024 + t];
    red[t] = acc;
    __syncthreads();
    for (int sft = 128; sft > 0; sft >>= 1) {
        if (t < sft) red[t] += red[t + sft];
        __syncthreads();
    }
    if (t == 0) out[b] = red[0] + fcb[0];
}

extern "C" void kernel_launch(void* const* d_in, const int* in_sizes, int n_in,
                              void* d_out, int out_size, void* d_ws, size_t ws_size,
                              hipStream_t stream)
{
    const float* x       = (const float*)d_in[0];
    const float* addl    = (const float*)d_in[1];
    const float* enc_Wih = (const float*)d_in[2];
    const float* enc_Whh = (const float*)d_in[3];
    const float* enc_bih = (const float*)d_in[4];
    const float* enc_bhh = (const float*)d_in[5];
    const float* dec_Wih = (const float*)d_in[6];
    const float* dec_Whh = (const float*)d_in[7];
    const float* dec_bih = (const float*)d_in[8];
    const float* dec_bhh = (const float*)d_in[9];
    const float* fcc_W   = (const float*)d_in[10];
    const float* fcc_b   = (const float*)d_in[11];
    const float* fc_W    = (const float*)d_in[12];
    const float* fc_b    = (const float*)d_in[13];
    const float* prelu_a = (const float*)d_in[14];

    float* ws = (float*)d_ws;
    float* h0 = ws;                        // [64][1024]
    float* h1 = ws + B_DIM * H_DIM;        // [64][1024]
    float* cT = ws + 2 * B_DIM * H_DIM;    // [1024][64]

    hipMemsetAsync(h0, 0, (size_t)B_DIM * H_DIM * sizeof(float), stream);
    hipMemsetAsync(cT, 0, (size_t)B_DIM * H_DIM * sizeof(float), stream);

    // Encoder: h0 -> ... ; after 256 steps final h lands in h0.
    for (int t = 0; t < T_DIM; ++t) {
        const float* hi = (t & 1) ? h1 : h0;
        float*       ho = (t & 1) ? h0 : h1;
        lstm_step_kernel<<<256, 256, 0, stream>>>(hi, ho, cT, x, t,
                                                  enc_Wih, enc_Whh, enc_bih, enc_bhh);
    }
    // Decoder: continues from (eh, ec); final dh lands in h0.
    for (int t = 0; t < T_DIM; ++t) {
        const float* hi = (t & 1) ? h1 : h0;
        float*       ho = (t & 1) ? h0 : h1;
        lstm_step_kernel<<<256, 256, 0, stream>>>(hi, ho, cT, x, t,
                                                  dec_Wih, dec_Whh, dec_bih, dec_bhh);
    }
    tail_kernel<<<64, 256, 0, stream>>>(h0, addl, fcc_W, fcc_b, fc_W, fc_b,
                                        prelu_a, (float*)d_out);
}

// Round 2
// 6132.463 us; speedup vs baseline: 3.7414x; 3.7414x over previous
//
#include <hip/hip_runtime.h>
#include <cmath>

typedef _Float16 f16;
typedef _Float16 f16x8 __attribute__((ext_vector_type(8)));
typedef _Float16 f16x4 __attribute__((ext_vector_type(4)));
typedef float f32x4 __attribute__((ext_vector_type(4)));

#define H_DIM 1024
#define I_DIMM 256
#define B_DIM 64
#define T_DIM 256
#define K_DIM 1280

// Build W16[4096][1280] = fp16([Whh | Wih]) row-major. grid = 4096 blocks.
__global__ __launch_bounds__(256) void conv_w_kernel(const float* __restrict__ Whh,
                                                     const float* __restrict__ Wih,
                                                     f16* __restrict__ W16) {
    const int r = blockIdx.x;
    const int tid = threadIdx.x;
    const float* hh = Whh + (size_t)r * H_DIM;
    const float* ih = Wih + (size_t)r * I_DIMM;
    f16* dst = W16 + (size_t)r * K_DIM;
    for (int k = tid; k < K_DIM; k += 256)
        dst[k] = (f16)(k < H_DIM ? hh[k] : ih[k - H_DIM]);
}

// x fp32 -> fp16, vectorized 4-wide. n4 = total/4.
__global__ __launch_bounds__(256) void conv_x_kernel(const float* __restrict__ x,
                                                     f16* __restrict__ x16, int n4) {
    const int i = blockIdx.x * 256 + threadIdx.x;
    if (i < n4) {
        float4 v = ((const float4*)x)[i];
        f16x4 o;
        o[0] = (f16)v.x; o[1] = (f16)v.y; o[2] = (f16)v.z; o[3] = (f16)v.w;
        ((f16x4*)x16)[i] = o;
    }
}

// One LSTM timestep via fp16 MFMA.
// grid = 256 blocks x 256 threads (4 waves). Block owns h-cols [blk*4,blk*4+4)
// x 4 gates = 16 W rows. Wave w computes D[16 batch x 16 gate] over full K=1280.
// n = lane&15 -> (gate g = n>>2, col j = n&3); kg = lane>>4 -> k-subgroup.
// Operand A (activations): row = lane&15 (batch), 8 consecutive k at kg*8.
// Operand B (W^T): col = lane&15 (gate row of W), 8 consecutive k at kg*8.
// D: col = lane&15 (gate), row = 4*kg + reg (batch-within-tile).
__global__ __launch_bounds__(256) void lstm_step_f16(
    const f16* __restrict__ h_in,    // [64][1024] fp16
    f16* __restrict__ h_out,         // [64][1024] fp16
    float* __restrict__ c_T,         // [1024][64] fp32 (transposed cell state)
    const f16* __restrict__ x16,     // [64][256][256] fp16
    int t,
    const f16* __restrict__ W16,     // [4096][1280] fp16
    const float* __restrict__ bih,   // [4096]
    const float* __restrict__ bhh)   // [4096]
{
    __shared__ float gl[64][17];     // [batch][n], +1 pad

    const int tid  = threadIdx.x;
    const int blk  = blockIdx.x;
    const int w    = tid >> 6;
    const int lane = tid & 63;
    const int n    = lane & 15;
    const int kg   = lane >> 4;

    const int rW = (n >> 2) * H_DIM + blk * 4 + (n & 3);
    const f16* pw = W16 + (size_t)rW * K_DIM + kg * 8;
    const int bA = w * 16 + n;
    const f16* pa = h_in + (size_t)bA * H_DIM + kg * 8;

    f32x4 acc[4];
    #pragma unroll
    for (int q = 0; q < 4; ++q) acc[q] = (f32x4){0.f, 0.f, 0.f, 0.f};

    // h part: k in [0, 1024)
    #pragma unroll 8
    for (int it = 0; it < 32; ++it) {
        f16x8 a = *(const f16x8*)(pa + it * 32);
        f16x8 b = *(const f16x8*)(pw + it * 32);
        acc[it & 3] = __builtin_amdgcn_mfma_f32_16x16x32_f16(a, b, acc[it & 3], 0, 0, 0);
    }
    // x part: k in [1024, 1280)
    const f16* px  = x16 + (size_t)bA * (T_DIM * I_DIMM) + t * I_DIMM + kg * 8;
    const f16* pw2 = pw + H_DIM;
    #pragma unroll
    for (int it = 0; it < 8; ++it) {
        f16x8 a = *(const f16x8*)(px + it * 32);
        f16x8 b = *(const f16x8*)(pw2 + it * 32);
        acc[it & 3] = __builtin_amdgcn_mfma_f32_16x16x32_f16(a, b, acc[it & 3], 0, 0, 0);
    }
    f32x4 s = acc[0] + acc[1] + acc[2] + acc[3];
    #pragma unroll
    for (int r = 0; r < 4; ++r)
        gl[w * 16 + kg * 4 + r][n] = s[r];
    __syncthreads();

    // activations + state update: thread -> (batch b, h-col j)
    const int b   = tid >> 2;
    const int j   = tid & 3;
    const int col = blk * 4 + j;
    float pre[4];
    #pragma unroll
    for (int g = 0; g < 4; ++g)
        pre[g] = gl[b][g * 4 + j] + bih[g * H_DIM + col] + bhh[g * H_DIM + col];
    const float i_ = 1.f / (1.f + expf(-pre[0]));
    const float f_ = 1.f / (1.f + expf(-pre[1]));
    const float g_ = tanhf(pre[2]);
    const float o_ = 1.f / (1.f + expf(-pre[3]));
    const float cn = f_ * c_T[col * 64 + b] + i_ * g_;
    c_T[col * 64 + b] = cn;
    h_out[(size_t)b * H_DIM + col] = (f16)(o_ * tanhf(cn));
}

// Tail MLP: a = PReLU(additional @ fcc_W^T + fcc_b); out[b] = [dh, a] @ fc_W^T + fc_b
__global__ __launch_bounds__(256) void tail_kernel(
    const f16* __restrict__ dh,        // [64][1024] fp16
    const float* __restrict__ addl,    // [64][128]
    const float* __restrict__ fccW,    // [256][128]
    const float* __restrict__ fccb,    // [256]
    const float* __restrict__ fcW,     // [1][1280]
    const float* __restrict__ fcb,     // [1]
    const float* __restrict__ prelu_a, // [1]
    float* __restrict__ out)           // [64]
{
    __shared__ float a_lds[256];
    __shared__ float red[256];
    const int b = blockIdx.x;
    const int t = threadIdx.x;

    float s = fccb[t];
    const float* wr = fccW + t * 128;
    const float* ar = addl + b * 128;
    #pragma unroll 4
    for (int k = 0; k < 128; ++k) s += ar[k] * wr[k];
    const float pa = *prelu_a;
    a_lds[t] = (s >= 0.f) ? s : pa * s;
    __syncthreads();

    float acc = 0.f;
    for (int k = t; k < 1024; k += 256) acc += (float)dh[b * H_DIM + k] * fcW[k];
    acc += a_lds[t] * fcW[1024 + t];
    red[t] = acc;
    __syncthreads();
    for (int sft = 128; sft > 0; sft >>= 1) {
        if (t < sft) red[t] += red[t + sft];
        __syncthreads();
    }
    if (t == 0) out[b] = red[0] + fcb[0];
}

extern "C" void kernel_launch(void* const* d_in, const int* in_sizes, int n_in,
                              void* d_out, int out_size, void* d_ws, size_t ws_size,
                              hipStream_t stream)
{
    const float* x       = (const float*)d_in[0];
    const float* addl    = (const float*)d_in[1];
    const float* enc_Wih = (const float*)d_in[2];
    const float* enc_Whh = (const float*)d_in[3];
    const float* enc_bih = (const float*)d_in[4];
    const float* enc_bhh = (const float*)d_in[5];
    const float* dec_Wih = (const float*)d_in[6];
    const float* dec_Whh = (const float*)d_in[7];
    const float* dec_bih = (const float*)d_in[8];
    const float* dec_bhh = (const float*)d_in[9];
    const float* fcc_W   = (const float*)d_in[10];
    const float* fcc_b   = (const float*)d_in[11];
    const float* fc_W    = (const float*)d_in[12];
    const float* fc_b    = (const float*)d_in[13];
    const float* prelu_a = (const float*)d_in[14];

    char* ws = (char*)d_ws;
    const size_t W16_BYTES = (size_t)4 * H_DIM * K_DIM * sizeof(f16);   // 10.5 MB
    const size_t X16_BYTES = (size_t)B_DIM * T_DIM * I_DIMM * sizeof(f16);
    const size_t H16_BYTES = (size_t)B_DIM * H_DIM * sizeof(f16);

    f16* W16e = (f16*)ws;                       ws += W16_BYTES;
    f16* W16d = (f16*)ws;                       ws += W16_BYTES;
    f16* x16  = (f16*)ws;                       ws += X16_BYTES;
    f16* h0   = (f16*)ws;                       ws += H16_BYTES;
    f16* h1   = (f16*)ws;                       ws += H16_BYTES;
    float* cT = (float*)ws;

    // One-time (per call) conversions.
    conv_w_kernel<<<4 * H_DIM, 256, 0, stream>>>(enc_Whh, enc_Wih, W16e);
    conv_w_kernel<<<4 * H_DIM, 256, 0, stream>>>(dec_Whh, dec_Wih, W16d);
    conv_x_kernel<<<(B_DIM * T_DIM * I_DIMM / 4 + 255) / 256, 256, 0, stream>>>(
        x, x16, B_DIM * T_DIM * I_DIMM / 4);
    hipMemsetAsync(h0, 0, H16_BYTES, stream);
    hipMemsetAsync(cT, 0, (size_t)H_DIM * B_DIM * sizeof(float), stream);

    // Encoder: after 256 steps final h lands in h0.
    for (int t = 0; t < T_DIM; ++t) {
        const f16* hi = (t & 1) ? h1 : h0;
        f16*       ho = (t & 1) ? h0 : h1;
        lstm_step_f16<<<256, 256, 0, stream>>>(hi, ho, cT, x16, t, W16e, enc_bih, enc_bhh);
    }
    // Decoder: continues from (eh, ec); final dh lands in h0.
    for (int t = 0; t < T_DIM; ++t) {
        const f16* hi = (t & 1) ? h1 : h0;
        f16*       ho = (t & 1) ? h0 : h1;
        lstm_step_f16<<<256, 256, 0, stream>>>(hi, ho, cT, x16, t, W16d, dec_bih, dec_bhh);
    }
    tail_kernel<<<64, 256, 0, stream>>>(h0, addl, fcc_W, fcc_b, fc_W, fc_b,
                                        prelu_a, (float*)d_out);
}